// Round 4
// baseline (161.329 us; speedup 1.0000x reference)
//
#include <hip/hip_runtime.h>
#include <cstdint>

#define TPB 256
#define PRE_PB 256     // prefix columns taken from EACH batch (2*PRE_PB total)

// ---------------------------------------------------------------------------
// Kernel 1 (fused prep + split-prefix decide).
// Per thread (one row i):
//   gt = R*kp + t, |gt|^2  -> gt4[i];  thr[i] = clamped self-distance d(i,i).
// Per block: redundantly recompute prefix gt4 rows into LDS.  Prefix columns
// are [0,PRE_PB) u [N, N+PRE_PB): 256 columns from EACH batch, so every row
// faces 256 same-batch columns -> survivors ~ M/257 ~ 64 INDEPENDENT of pose
// geometry (fixes the batch-0-only prefix failing to filter batch-1 rows).
// bad iff exists prefix j<i with clamp(v)<=dii or j>i with clamp(v)<dii.
// All arithmetic bit-matches the validated baseline (absmax=0.0): dot via
// ascending-k FMA chain, sums via (a+b)+c with contraction off, 2*dot via
// pre-scaled operands (exact), clamp commutes with min, j==i self-compare is
// bitwise-equal and never triggers.
// ---------------------------------------------------------------------------
__global__ void __launch_bounds__(TPB) fused_prep_prefix(
        const float* __restrict__ kp_before,
        const float* __restrict__ pred,
        const float* __restrict__ pose,
        float4* __restrict__ gt4,
        float* __restrict__ thr,
        unsigned int* __restrict__ good,
        float* __restrict__ accum,
        int M, int N) {
    __shared__ float4 shg[2 * PRE_PB];
    int tid = threadIdx.x;
    int i = blockIdx.x * TPB + tid;

    if (blockIdx.x == 0 && tid < 8) accum[tid] = 0.0f;  // incl. ticket @ [7]

    float sp = 0.f, tp0 = 0.f, tp1 = 0.f, tp2 = 0.f, dii = 0.f;
    if (i < M) {
        int b = i / N;
        const float* P = pose + b * 12;
        float k0 = kp_before[3*i+0];
        float k1 = kp_before[3*i+1];
        float k2 = kp_before[3*i+2];
        float g0 = fmaf(P[2],  k2, fmaf(P[1], k1, P[0]*k0)) + P[3];
        float g1 = fmaf(P[6],  k2, fmaf(P[5], k1, P[4]*k0)) + P[7];
        float g2 = fmaf(P[10], k2, fmaf(P[9], k1, P[8]*k0)) + P[11];
        float sg;
        {
            #pragma clang fp contract(off)
            sg = (g0*g0 + g1*g1) + g2*g2;   // numpy sum order, no FMA
        }
        gt4[i] = make_float4(g0, g1, g2, sg);

        float p0 = pred[3*i+0], p1 = pred[3*i+1], p2 = pred[3*i+2];
        {
            #pragma clang fp contract(off)
            sp = (p0*p0 + p1*p1) + p2*p2;
        }
        tp0 = 2.0f*p0; tp1 = 2.0f*p1; tp2 = 2.0f*p2;
        float dot2 = fmaf(tp2, g2, fmaf(tp1, g1, tp0*g0));
        float v = (sp + sg) - dot2;
        dii = fmaxf(v, 0.0f);
        thr[i] = dii;
    }

    // redundant per-block recompute of the two prefix tiles into LDS
    // (bitwise identical expression/inputs -> identical bits to gt4[])
    #pragma unroll
    for (int half = 0; half < 2; half++) {
        int jp = (half == 0) ? tid : (N + tid);
        if (jp >= M) jp = tid;              // B==1 fallback: duplicate tile
        const float* Pj = pose + (jp / N) * 12;
        float q0 = kp_before[3*jp+0];
        float q1 = kp_before[3*jp+1];
        float q2 = kp_before[3*jp+2];
        float h0 = fmaf(Pj[2],  q2, fmaf(Pj[1], q1, Pj[0]*q0)) + Pj[3];
        float h1 = fmaf(Pj[6],  q2, fmaf(Pj[5], q1, Pj[4]*q0)) + Pj[7];
        float h2 = fmaf(Pj[10], q2, fmaf(Pj[9], q1, Pj[8]*q0)) + Pj[11];
        float hh;
        {
            #pragma clang fp contract(off)
            hh = (h0*h0 + h1*h1) + h2*h2;
        }
        shg[half * PRE_PB + tid] = make_float4(h0, h1, h2, hh);
    }
    __syncthreads();

    if (i >= M) return;

    bool bad;
    bool cleanB = (i >= PRE_PB) && (i < N);        // tile0 all j<i, tile1 all j>i
    bool cleanA = (i >= N + PRE_PB);               // both tiles all j<i
    if (cleanA) {
        float mn = __uint_as_float(0x7f7fffffu);   // FLT_MAX
        for (int k = 0; k < 2 * PRE_PB; k++) {
            float4 g = shg[k];
            float v = (sp + g.w) -
                      fmaf(tp2, g.z, fmaf(tp1, g.y, tp0 * g.x));
            mn = fminf(mn, v);
        }
        bad = (fmaxf(mn, 0.0f) <= dii);
    } else if (cleanB) {
        float mnl = __uint_as_float(0x7f7fffffu);
        float mnr = __uint_as_float(0x7f7fffffu);
        for (int k = 0; k < PRE_PB; k++) {
            float4 g = shg[k];
            float v = (sp + g.w) -
                      fmaf(tp2, g.z, fmaf(tp1, g.y, tp0 * g.x));
            mnl = fminf(mnl, v);
        }
        for (int k = PRE_PB; k < 2 * PRE_PB; k++) {
            float4 g = shg[k];
            float v = (sp + g.w) -
                      fmaf(tp2, g.z, fmaf(tp1, g.y, tp0 * g.x));
            mnr = fminf(mnr, v);
        }
        bad = (fmaxf(mnl, 0.0f) <= dii) || (fmaxf(mnr, 0.0f) < dii);
    } else {
        // rows inside a prefix tile (i<PRE_PB or N<=i<N+PRE_PB): generic scan
        // with explicit column index; only 2 of 64 blocks take this path.
        bool h = false;
        for (int k = 0; k < 2 * PRE_PB; k++) {
            int j = (k < PRE_PB) ? k : (N + k - PRE_PB);
            if (j >= M) j = k - PRE_PB;            // B==1 fallback (dup tile)
            float4 g = shg[k];
            float v = (sp + g.w) -
                      fmaf(tp2, g.z, fmaf(tp1, g.y, tp0 * g.x));
            float c = fmaxf(v, 0.0f);
            h = h || (c < dii && j != i) || (c == dii && j < i);
        }
        bad = h;
    }
    good[i] = bad ? 0u : 1u;
}

// ---------------------------------------------------------------------------
// Kernel 2 (fused resolve + finalize + scalar).
// One block per 256-row range.  Gather this range's prefix survivors
// (expected ~1 per range, ~64 total), resolve each against the non-prefix
// columns [PRE_PB, N) u [N+PRE_PB, M) with all 256 threads (verdicts into
// LDS), then immediately compute the range's BCE/L1 partial sums, atomicAdd
// into accum, and let the last block (ticket in accum[7]) combine the
// final scalar.  Saves one launch and the good[] round-trip for finalize.
// ---------------------------------------------------------------------------
__device__ inline float wave_red(float v) {
    #pragma unroll
    for (int off = 32; off > 0; off >>= 1) v += __shfl_down(v, off, 64);
    return v;
}

__global__ void __launch_bounds__(TPB) resolve_finalize(
        const float* __restrict__ pred,
        const float4* __restrict__ gt4,
        const float* __restrict__ thr,
        const unsigned int* __restrict__ good,
        const float* __restrict__ ow,
        const float* __restrict__ logits,
        float* __restrict__ accum,
        float* __restrict__ out,
        int M, int N) {
    __shared__ int cands[TPB];
    __shared__ int ncand;
    __shared__ unsigned char verd[TPB];
    int tid = threadIdx.x;
    int r0 = blockIdx.x * TPB;
    int i = r0 + tid;

    if (tid == 0) ncand = 0;
    __syncthreads();
    unsigned int gi = (i < M) ? good[i] : 0u;
    verd[tid] = (unsigned char)gi;
    if (i < M && gi) { int p = atomicAdd(&ncand, 1); cands[p] = i; }
    __syncthreads();
    int nc = ncand;

    for (int e = 0; e < nc; e++) {
        int r = cands[e];
        float p0 = pred[3*r+0], p1 = pred[3*r+1], p2 = pred[3*r+2];
        float sp;
        {
            #pragma clang fp contract(off)
            sp = (p0*p0 + p1*p1) + p2*p2;
        }
        float tp0 = 2.0f*p0, tp1 = 2.0f*p1, tp2 = 2.0f*p2;
        float dii = thr[r];
        bool h = false;
        for (int j = PRE_PB + tid; j < N; j += TPB) {
            float4 g = gt4[j];
            float v = (sp + g.w) -
                      fmaf(tp2, g.z, fmaf(tp1, g.y, tp0 * g.x));
            float c = fmaxf(v, 0.0f);
            h = h || (c < dii && j != r) || (c == dii && j < r);
        }
        for (int j = N + PRE_PB + tid; j < M; j += TPB) {
            float4 g = gt4[j];
            float v = (sp + g.w) -
                      fmaf(tp2, g.z, fmaf(tp1, g.y, tp0 * g.x));
            float c = fmaxf(v, 0.0f);
            h = h || (c < dii && j != r) || (c == dii && j < r);
        }
        if (h) verd[r - r0] = 0;   // benign race: only 0 is written
    }
    __syncthreads();

    // finalize: one row per thread, verdict from LDS
    float werr = 0.f, wsum = 0.f, b1 = 0.f, c1 = 0.f, b0 = 0.f, c0 = 0.f;
    if (i < M) {
        float x = logits[i];
        float l1p = log1pf(expf(-fabsf(x)));   // softplus tail
        if (verd[tid]) {                       // label 1: bce = softplus(-x)
            b1 = fmaxf(-x, 0.f) + l1p; c1 = 1.f;
        } else {                               // label 0: bce = softplus(x)
            b0 = fmaxf(x, 0.f) + l1p;  c0 = 1.f;
        }
        float4 g = gt4[i];
        float p0 = pred[3*i+0], p1 = pred[3*i+1], p2 = pred[3*i+2];
        float e = (fabsf(p0 - g.x) + fabsf(p1 - g.y)) + fabsf(p2 - g.z);
        float wi = ow[i];
        werr = wi * e;
        wsum = wi;
    }
    werr = wave_red(werr); wsum = wave_red(wsum);
    b1 = wave_red(b1); c1 = wave_red(c1);
    b0 = wave_red(b0); c0 = wave_red(c0);
    if ((tid & 63) == 0) {
        atomicAdd(&accum[0], werr);
        atomicAdd(&accum[1], wsum);
        atomicAdd(&accum[2], b1);
        atomicAdd(&accum[3], c1);
        atomicAdd(&accum[4], b0);
        atomicAdd(&accum[5], c0);
    }
    __threadfence();          // make this block's atomics device-visible
    __syncthreads();
    if (tid == 0) {
        unsigned int* ctr = (unsigned int*)&accum[7];
        unsigned int old = atomicAdd(ctr, 1u);
        if (old == gridDim.x - 1) {
            // atomic reads: guaranteed-coherent path for others' atomics
            float a0 = atomicAdd(&accum[0], 0.f);
            float a1 = atomicAdd(&accum[1], 0.f);
            float a2 = atomicAdd(&accum[2], 0.f);
            float a3 = atomicAdd(&accum[3], 0.f);
            float a4 = atomicAdd(&accum[4], 0.f);
            float a5 = atomicAdd(&accum[5], 0.f);
            float mean_err = a0 / fmaxf(a1, 1e-6f);
            float g1v = (a3 > 0.f) ? (a2 / fmaxf(a3, 1.f)) : 0.f;
            float g0v = (a5 > 0.f) ? (a4 / fmaxf(a5, 1.f)) : 0.f;
            out[0] = mean_err + (g0v * 0.5f + g1v * 0.5f);
        }
    }
}

extern "C" void kernel_launch(void* const* d_in, const int* in_sizes, int n_in,
                              void* d_out, int out_size, void* d_ws, size_t ws_size,
                              hipStream_t stream) {
    const float* kp_before = (const float*)d_in[0];
    const float* pred      = (const float*)d_in[1];
    const float* pose      = (const float*)d_in[2];
    const float* ow        = (const float*)d_in[3];
    const float* logits    = (const float*)d_in[4];
    float* out = (float*)d_out;

    int M = in_sizes[3];            // B*N = 16384
    int B = in_sizes[2] / 12;       // 2
    int N = M / B;                  // 8192

    char* ws = (char*)d_ws;
    float4* gt4 = (float4*)ws;                                  // M*16 B
    float* thr = (float*)(ws + (size_t)M * 16);                 // M*4 B
    unsigned int* good = (unsigned int*)(ws + (size_t)M * 20);  // M*4 B
    float* accum = (float*)(ws + (size_t)M * 24);               // 32 B ([7]=ticket)

    int nrb = (M + TPB - 1) / TPB;                              // 64 row-blocks

    hipLaunchKernelGGL(fused_prep_prefix, dim3(nrb), dim3(TPB), 0, stream,
                       kp_before, pred, pose, gt4, thr, good, accum, M, N);

    hipLaunchKernelGGL(resolve_finalize, dim3(nrb), dim3(TPB), 0, stream,
                       pred, gt4, thr, good, ow, logits, accum, out, M, N);
}

// Round 5
// 122.351 us; speedup vs baseline: 1.3186x; 1.3186x over previous
//
#include <hip/hip_runtime.h>
#include <cstdint>

#define TPB 256
#define PRE_PB 256     // prefix columns taken from EACH batch (2*PRE_PB total)
#define NSLICE 16      // resolve j-slices per row-range

// ---------------------------------------------------------------------------
// Kernel 1 (fused prep + split-prefix decide).  [unchanged from R4, validated]
// Per thread (one row i):
//   gt = R*kp + t, |gt|^2  -> gt4[i];  thr[i] = clamped self-distance d(i,i).
// Per block: redundantly recompute prefix gt4 rows into LDS.  Prefix columns
// are [0,PRE_PB) u [N, N+PRE_PB): 256 columns from EACH batch, so every row
// faces 256 same-batch columns -> survivors ~ M/257 ~ 64 independent of pose
// geometry.  bad iff exists prefix j<i with clamp(v)<=dii or j>i with
// clamp(v)<dii.  All arithmetic bit-matches the validated baseline.
// ---------------------------------------------------------------------------
__global__ void __launch_bounds__(TPB) fused_prep_prefix(
        const float* __restrict__ kp_before,
        const float* __restrict__ pred,
        const float* __restrict__ pose,
        float4* __restrict__ gt4,
        float* __restrict__ thr,
        unsigned int* __restrict__ good,
        float* __restrict__ accum,
        int M, int N) {
    __shared__ float4 shg[2 * PRE_PB];
    int tid = threadIdx.x;
    int i = blockIdx.x * TPB + tid;

    if (blockIdx.x == 0 && tid < 8) accum[tid] = 0.0f;  // incl. ticket @ [7]

    float sp = 0.f, tp0 = 0.f, tp1 = 0.f, tp2 = 0.f, dii = 0.f;
    if (i < M) {
        int b = i / N;
        const float* P = pose + b * 12;
        float k0 = kp_before[3*i+0];
        float k1 = kp_before[3*i+1];
        float k2 = kp_before[3*i+2];
        float g0 = fmaf(P[2],  k2, fmaf(P[1], k1, P[0]*k0)) + P[3];
        float g1 = fmaf(P[6],  k2, fmaf(P[5], k1, P[4]*k0)) + P[7];
        float g2 = fmaf(P[10], k2, fmaf(P[9], k1, P[8]*k0)) + P[11];
        float sg;
        {
            #pragma clang fp contract(off)
            sg = (g0*g0 + g1*g1) + g2*g2;   // numpy sum order, no FMA
        }
        gt4[i] = make_float4(g0, g1, g2, sg);

        float p0 = pred[3*i+0], p1 = pred[3*i+1], p2 = pred[3*i+2];
        {
            #pragma clang fp contract(off)
            sp = (p0*p0 + p1*p1) + p2*p2;
        }
        tp0 = 2.0f*p0; tp1 = 2.0f*p1; tp2 = 2.0f*p2;
        float dot2 = fmaf(tp2, g2, fmaf(tp1, g1, tp0*g0));
        float v = (sp + sg) - dot2;
        dii = fmaxf(v, 0.0f);
        thr[i] = dii;
    }

    // redundant per-block recompute of the two prefix tiles into LDS
    // (bitwise identical expression/inputs -> identical bits to gt4[])
    #pragma unroll
    for (int half = 0; half < 2; half++) {
        int jp = (half == 0) ? tid : (N + tid);
        if (jp >= M) jp = tid;              // B==1 fallback: duplicate tile
        const float* Pj = pose + (jp / N) * 12;
        float q0 = kp_before[3*jp+0];
        float q1 = kp_before[3*jp+1];
        float q2 = kp_before[3*jp+2];
        float h0 = fmaf(Pj[2],  q2, fmaf(Pj[1], q1, Pj[0]*q0)) + Pj[3];
        float h1 = fmaf(Pj[6],  q2, fmaf(Pj[5], q1, Pj[4]*q0)) + Pj[7];
        float h2 = fmaf(Pj[10], q2, fmaf(Pj[9], q1, Pj[8]*q0)) + Pj[11];
        float hh;
        {
            #pragma clang fp contract(off)
            hh = (h0*h0 + h1*h1) + h2*h2;
        }
        shg[half * PRE_PB + tid] = make_float4(h0, h1, h2, hh);
    }
    __syncthreads();

    if (i >= M) return;

    bool bad;
    bool cleanB = (i >= PRE_PB) && (i < N);        // tile0 all j<i, tile1 all j>i
    bool cleanA = (i >= N + PRE_PB);               // both tiles all j<i
    if (cleanA) {
        float mn = __uint_as_float(0x7f7fffffu);   // FLT_MAX
        for (int k = 0; k < 2 * PRE_PB; k++) {
            float4 g = shg[k];
            float v = (sp + g.w) -
                      fmaf(tp2, g.z, fmaf(tp1, g.y, tp0 * g.x));
            mn = fminf(mn, v);
        }
        bad = (fmaxf(mn, 0.0f) <= dii);
    } else if (cleanB) {
        float mnl = __uint_as_float(0x7f7fffffu);
        float mnr = __uint_as_float(0x7f7fffffu);
        for (int k = 0; k < PRE_PB; k++) {
            float4 g = shg[k];
            float v = (sp + g.w) -
                      fmaf(tp2, g.z, fmaf(tp1, g.y, tp0 * g.x));
            mnl = fminf(mnl, v);
        }
        for (int k = PRE_PB; k < 2 * PRE_PB; k++) {
            float4 g = shg[k];
            float v = (sp + g.w) -
                      fmaf(tp2, g.z, fmaf(tp1, g.y, tp0 * g.x));
            mnr = fminf(mnr, v);
        }
        bad = (fmaxf(mnl, 0.0f) <= dii) || (fmaxf(mnr, 0.0f) < dii);
    } else {
        // rows inside a prefix tile: generic scan with explicit column index
        bool h = false;
        for (int k = 0; k < 2 * PRE_PB; k++) {
            int j = (k < PRE_PB) ? k : (N + k - PRE_PB);
            if (j >= M) j = k - PRE_PB;            // B==1 fallback (dup tile)
            float4 g = shg[k];
            float v = (sp + g.w) -
                      fmaf(tp2, g.z, fmaf(tp1, g.y, tp0 * g.x));
            float c = fmaxf(v, 0.0f);
            h = h || (c < dii && j != i) || (c == dii && j < i);
        }
        bad = h;
    }
    good[i] = bad ? 0u : 1u;
}

// ---------------------------------------------------------------------------
// Kernel 2 (resolve): grid = (M/TPB ranges) x NSLICE slices.  Each block
// gathers its range's prefix survivors (expected ~1) and checks them against
// its ~992-column slice of the non-prefix columns.  Per candidate, each
// thread issues exactly 4 independent loads BEFORE any use -> one memory
// round trip per candidate (fixes R4's 62-deep serialized chain: worst block
// drops from ~250 to ~4 round trips).  Any hit -> good[r]=0 (benign race,
// idempotent; next-kernel boundary publishes it).
// ---------------------------------------------------------------------------
__global__ void __launch_bounds__(TPB) resolve_kernel(
        const float* __restrict__ pred,
        const float4* __restrict__ gt4,
        const float* __restrict__ thr,
        unsigned int* __restrict__ good,
        int M, int N) {
    __shared__ int cands[TPB];
    __shared__ int ncand;
    int tid = threadIdx.x;
    int s  = blockIdx.x % NSLICE;
    int r0 = (blockIdx.x / NSLICE) * TPB;
    if (tid == 0) ncand = 0;
    __syncthreads();
    int i = r0 + tid;
    if (i < M && good[i] == 1u) { int p = atomicAdd(&ncand, 1); cands[p] = i; }
    __syncthreads();
    int nc = ncand;
    if (nc == 0) return;

    // slice bounds over the two non-prefix column ranges
    int C0 = N - PRE_PB;
    int per0 = (C0 + NSLICE - 1) / NSLICE;
    int js0 = PRE_PB + s * per0;
    int je0 = js0 + per0; if (je0 > N) je0 = N;
    int C1 = (M - N) - PRE_PB; if (C1 < 0) C1 = 0;
    int per1 = (C1 + NSLICE - 1) / NSLICE;
    int js1 = N + PRE_PB + s * per1;
    int je1 = js1 + per1; if (je1 > M) je1 = M;

    for (int e = 0; e < nc; e++) {
        int r = cands[e];
        float p0 = pred[3*r+0], p1 = pred[3*r+1], p2 = pred[3*r+2];
        float sp;
        {
            #pragma clang fp contract(off)
            sp = (p0*p0 + p1*p1) + p2*p2;
        }
        float tp0 = 2.0f*p0, tp1 = 2.0f*p1, tp2 = 2.0f*p2;
        float dii = thr[r];

        // 4 independent loads, all issued before first use (one round trip)
        int ja0 = js0 + tid;        bool va0 = (ja0 < je0);
        int jb0 = ja0 + TPB;        bool vb0 = (jb0 < je0);
        int ja1 = js1 + tid;        bool va1 = (C1 > 0) && (ja1 < je1);
        int jb1 = ja1 + TPB;        bool vb1 = (C1 > 0) && (jb1 < je1);
        float4 gA0 = gt4[va0 ? ja0 : PRE_PB];
        float4 gB0 = gt4[vb0 ? jb0 : PRE_PB];
        float4 gA1 = gt4[va1 ? ja1 : PRE_PB];
        float4 gB1 = gt4[vb1 ? jb1 : PRE_PB];

        bool h = false;
        {
            float v = (sp + gA0.w) -
                      fmaf(tp2, gA0.z, fmaf(tp1, gA0.y, tp0 * gA0.x));
            float c = fmaxf(v, 0.0f);
            h = h || (va0 && ((c < dii && ja0 != r) || (c == dii && ja0 < r)));
        }
        {
            float v = (sp + gB0.w) -
                      fmaf(tp2, gB0.z, fmaf(tp1, gB0.y, tp0 * gB0.x));
            float c = fmaxf(v, 0.0f);
            h = h || (vb0 && ((c < dii && jb0 != r) || (c == dii && jb0 < r)));
        }
        {
            float v = (sp + gA1.w) -
                      fmaf(tp2, gA1.z, fmaf(tp1, gA1.y, tp0 * gA1.x));
            float c = fmaxf(v, 0.0f);
            h = h || (va1 && ((c < dii && ja1 != r) || (c == dii && ja1 < r)));
        }
        {
            float v = (sp + gB1.w) -
                      fmaf(tp2, gB1.z, fmaf(tp1, gB1.y, tp0 * gB1.x));
            float c = fmaxf(v, 0.0f);
            h = h || (vb1 && ((c < dii && jb1 != r) || (c == dii && jb1 < r)));
        }
        if (h) good[r] = 0u;    // benign: only 0 is ever written
    }
}

// ---------------------------------------------------------------------------
// Kernel 3: per-point BCE (balanced groups) + weighted L1; wave reduce,
// atomicAdd into accum[0..5]; last-block ticket (accum[7]) computes the
// final scalar.  [validated structure from R1 + R4 tail]
// ---------------------------------------------------------------------------
__device__ inline float wave_red(float v) {
    #pragma unroll
    for (int off = 32; off > 0; off >>= 1) v += __shfl_down(v, off, 64);
    return v;
}

__global__ void __launch_bounds__(TPB) finalize_kernel(
        const float* __restrict__ pred,
        const float4* __restrict__ gt4,
        const float* __restrict__ ow,
        const float* __restrict__ logits,
        const unsigned int* __restrict__ good,
        float* __restrict__ accum,
        float* __restrict__ out,
        int M) {
    float werr = 0.f, wsum = 0.f, b1 = 0.f, c1 = 0.f, b0 = 0.f, c0 = 0.f;
    int stride = gridDim.x * blockDim.x;
    for (int i = blockIdx.x * blockDim.x + threadIdx.x; i < M; i += stride) {
        float x = logits[i];
        float l1p = log1pf(expf(-fabsf(x)));   // softplus tail
        if (good[i] == 1u) {                   // label 1: bce = softplus(-x)
            b1 += fmaxf(-x, 0.f) + l1p; c1 += 1.f;
        } else {                               // label 0: bce = softplus(x)
            b0 += fmaxf(x, 0.f) + l1p;  c0 += 1.f;
        }
        float4 g = gt4[i];
        float p0 = pred[3*i+0], p1 = pred[3*i+1], p2 = pred[3*i+2];
        float e = (fabsf(p0 - g.x) + fabsf(p1 - g.y)) + fabsf(p2 - g.z);
        float wi = ow[i];
        werr += wi * e;
        wsum += wi;
    }
    werr = wave_red(werr); wsum = wave_red(wsum);
    b1 = wave_red(b1); c1 = wave_red(c1);
    b0 = wave_red(b0); c0 = wave_red(c0);
    if ((threadIdx.x & 63) == 0) {
        atomicAdd(&accum[0], werr);
        atomicAdd(&accum[1], wsum);
        atomicAdd(&accum[2], b1);
        atomicAdd(&accum[3], c1);
        atomicAdd(&accum[4], b0);
        atomicAdd(&accum[5], c0);
    }
    __threadfence();          // make this block's atomics device-visible
    __syncthreads();
    if (threadIdx.x == 0) {
        unsigned int* ctr = (unsigned int*)&accum[7];
        unsigned int old = atomicAdd(ctr, 1u);
        if (old == gridDim.x - 1) {
            // atomic reads: guaranteed-coherent path for others' atomics
            float a0 = atomicAdd(&accum[0], 0.f);
            float a1 = atomicAdd(&accum[1], 0.f);
            float a2 = atomicAdd(&accum[2], 0.f);
            float a3 = atomicAdd(&accum[3], 0.f);
            float a4 = atomicAdd(&accum[4], 0.f);
            float a5 = atomicAdd(&accum[5], 0.f);
            float mean_err = a0 / fmaxf(a1, 1e-6f);
            float g1v = (a3 > 0.f) ? (a2 / fmaxf(a3, 1.f)) : 0.f;
            float g0v = (a5 > 0.f) ? (a4 / fmaxf(a5, 1.f)) : 0.f;
            out[0] = mean_err + (g0v * 0.5f + g1v * 0.5f);
        }
    }
}

extern "C" void kernel_launch(void* const* d_in, const int* in_sizes, int n_in,
                              void* d_out, int out_size, void* d_ws, size_t ws_size,
                              hipStream_t stream) {
    const float* kp_before = (const float*)d_in[0];
    const float* pred      = (const float*)d_in[1];
    const float* pose      = (const float*)d_in[2];
    const float* ow        = (const float*)d_in[3];
    const float* logits    = (const float*)d_in[4];
    float* out = (float*)d_out;

    int M = in_sizes[3];            // B*N = 16384
    int B = in_sizes[2] / 12;       // 2
    int N = M / B;                  // 8192

    char* ws = (char*)d_ws;
    float4* gt4 = (float4*)ws;                                  // M*16 B
    float* thr = (float*)(ws + (size_t)M * 16);                 // M*4 B
    unsigned int* good = (unsigned int*)(ws + (size_t)M * 20);  // M*4 B
    float* accum = (float*)(ws + (size_t)M * 24);               // 32 B ([7]=ticket)

    int nrb = (M + TPB - 1) / TPB;                              // 64 row-blocks

    hipLaunchKernelGGL(fused_prep_prefix, dim3(nrb), dim3(TPB), 0, stream,
                       kp_before, pred, pose, gt4, thr, good, accum, M, N);

    hipLaunchKernelGGL(resolve_kernel, dim3(nrb * NSLICE), dim3(TPB), 0, stream,
                       pred, gt4, thr, good, M, N);

    hipLaunchKernelGGL(finalize_kernel, dim3(nrb), dim3(TPB), 0, stream,
                       pred, gt4, ow, logits, good, accum, out, M);
}

// Round 6
// 107.720 us; speedup vs baseline: 1.4977x; 1.1358x over previous
//
#include <hip/hip_runtime.h>
#include <cstdint>

#define TPB 256
#define PRE_PB 128       // prefix columns taken from EACH batch (2*PRE_PB = 256)
#define ROWS_PB 64       // rows per block (quad-split: 4 threads per row)
#define RBATCH 16        // resolve: loads issued per memory round trip

// ---------------------------------------------------------------------------
// Kernel 1 (prep + quad-split prefix decide).
// 4 threads per row; each scans 64 of the 256 prefix columns
// ([0,PRE_PB) u [N,N+PRE_PB)), combined via shfl_xor within the quad.
// Grid = M/64 blocks -> all 256 CUs busy; critical path 64 iterations
// (vs 512 in R5).  Prefix tile is stored interleaved in LDS
// (phys = (k&63)*4 + (k>>6)) so the 4 sub-columns of a quad read 4
// consecutive float4s -> conflict-free broadcast.
// Row i survives (good=1) iff no prefix j<i with clamp(v)<=dii and no
// prefix j>i with clamp(v)<dii.  Survivors ~ M/(2*PRE_PB+1) ~ 127.
// All arithmetic bit-matches the validated baseline (absmax=0.0): dot via
// ascending-k FMA chain, sums via (a+b)+c with contraction off, 2*dot via
// pre-scaled operands (exact), clamp commutes with min; min is
// order-independent so the quad-split changes no bits.
// ---------------------------------------------------------------------------
__global__ void __launch_bounds__(TPB) prep_prefix(
        const float* __restrict__ kp_before,
        const float* __restrict__ pred,
        const float* __restrict__ pose,
        float4* __restrict__ gt4,
        float* __restrict__ thr,
        unsigned int* __restrict__ good,
        float* __restrict__ accum,
        int M, int N) {
    __shared__ float4 shg[2 * PRE_PB];   // interleaved: (k&63)*4 + (k>>6)
    int tid = threadIdx.x;
    if (blockIdx.x == 0 && tid < 8) accum[tid] = 0.0f;  // incl. ticket @ [7]

    int row = blockIdx.x * ROWS_PB + (tid >> 2);
    int sub = tid & 3;
    bool rowvalid = (row < M);
    int i = rowvalid ? row : (M - 1);

    // --- row setup (each quad thread redundantly, bit-identical) ---
    float sp, tp0, tp1, tp2, dii;
    float g0, g1, g2, sg;
    {
        int b = i / N;
        const float* P = pose + b * 12;
        float k0 = kp_before[3*i+0];
        float k1 = kp_before[3*i+1];
        float k2 = kp_before[3*i+2];
        g0 = fmaf(P[2],  k2, fmaf(P[1], k1, P[0]*k0)) + P[3];
        g1 = fmaf(P[6],  k2, fmaf(P[5], k1, P[4]*k0)) + P[7];
        g2 = fmaf(P[10], k2, fmaf(P[9], k1, P[8]*k0)) + P[11];
        {
            #pragma clang fp contract(off)
            sg = (g0*g0 + g1*g1) + g2*g2;   // numpy sum order, no FMA
        }
        float p0 = pred[3*i+0], p1 = pred[3*i+1], p2 = pred[3*i+2];
        {
            #pragma clang fp contract(off)
            sp = (p0*p0 + p1*p1) + p2*p2;
        }
        tp0 = 2.0f*p0; tp1 = 2.0f*p1; tp2 = 2.0f*p2;
        float dot2 = fmaf(tp2, g2, fmaf(tp1, g1, tp0*g0));
        float v = (sp + sg) - dot2;
        dii = fmaxf(v, 0.0f);
    }
    if (sub == 0 && rowvalid) {
        gt4[i] = make_float4(g0, g1, g2, sg);
        thr[i] = dii;
    }

    // --- prefix tile recompute into LDS (256 threads -> 256 entries) ---
    {
        int k = tid;                               // logical prefix col index
        int jp = (k < PRE_PB) ? k : (N + k - PRE_PB);
        if (jp >= M) jp = k - PRE_PB;              // B==1 fallback: dup tile0
        const float* Pj = pose + (jp / N) * 12;
        float q0 = kp_before[3*jp+0];
        float q1 = kp_before[3*jp+1];
        float q2 = kp_before[3*jp+2];
        float h0 = fmaf(Pj[2],  q2, fmaf(Pj[1], q1, Pj[0]*q0)) + Pj[3];
        float h1 = fmaf(Pj[6],  q2, fmaf(Pj[5], q1, Pj[4]*q0)) + Pj[7];
        float h2 = fmaf(Pj[10], q2, fmaf(Pj[9], q1, Pj[8]*q0)) + Pj[11];
        float hh;
        {
            #pragma clang fp contract(off)
            hh = (h0*h0 + h1*h1) + h2*h2;
        }
        shg[(k & 63) * 4 + (k >> 6)] = make_float4(h0, h1, h2, hh);
    }
    __syncthreads();

    // --- scan: this thread's 64 columns are logical k = sub*64 + it ---
    bool dirty = (i < PRE_PB) || (i >= N && i < N + PRE_PB);
    bool bad;
    if (!dirty) {
        float mn = __uint_as_float(0x7f7fffffu);   // FLT_MAX
        #pragma unroll 8
        for (int it = 0; it < 64; it++) {
            float4 g = shg[it * 4 + sub];
            float v = (sp + g.w) -
                      fmaf(tp2, g.z, fmaf(tp1, g.y, tp0 * g.x));
            mn = fminf(mn, v);
        }
        // quad combine: after xor1, lanes{0,1}=min(tile0 halves)=mnl,
        // lanes{2,3}=mnr; xor2 brings the other pair across.
        float v1 = fminf(mn, __shfl_xor(mn, 1, 64));
        float v2 = __shfl_xor(v1, 2, 64);
        if (i >= N + PRE_PB) {
            // both tiles entirely j < i
            float mall = fminf(v1, v2);
            bad = (fmaxf(mall, 0.0f) <= dii);
        } else {
            // PRE_PB <= i < N: tile0 all j<i (<=), tile1 all j>i (<)
            // at sub==0: v1 = mnl, v2 = mnr  (only sub==0's result is used)
            bad = (fmaxf(v1, 0.0f) <= dii) || (fmaxf(v2, 0.0f) < dii);
        }
    } else {
        // rows inside a prefix tile: generic predicate with explicit j
        bool h = false;
        #pragma unroll 8
        for (int it = 0; it < 64; it++) {
            int k = sub * 64 + it;
            int j = (k < PRE_PB) ? k : (N + k - PRE_PB);
            if (j >= M) j = k - PRE_PB;            // B==1 fallback (dup tile)
            float4 g = shg[it * 4 + sub];
            float v = (sp + g.w) -
                      fmaf(tp2, g.z, fmaf(tp1, g.y, tp0 * g.x));
            float c = fmaxf(v, 0.0f);
            h = h || (c < dii && j != i) || (c == dii && j < i);
        }
        int hv = h ? 1 : 0;
        hv |= __shfl_xor(hv, 1, 64);
        hv |= __shfl_xor(hv, 2, 64);
        bad = (hv != 0);
    }
    if (sub == 0 && rowvalid) good[i] = bad ? 0u : 1u;
}

// ---------------------------------------------------------------------------
// Kernel 2 (resolve + finalize + scalar, fused).
// One block per 64-row range (256 blocks).  Gather the range's prefix
// survivors (expected ~0.5), resolve each against ALL non-prefix columns
// with 256 threads: per candidate ~62 cols/thread in 4 batches of RBATCH=16
// pre-issued loads -> 4 memory round trips, no serial chain (R5-validated
// flat pattern).  Verdicts land in LDS; then the block finalizes its own 64
// rows (BCE + weighted L1), wave-reduces (summation groups = contiguous
// 64 rows, identical to all prior passing rounds), atomicAdds into accum,
// and the last block (ticket @ accum[7]) combines the final scalar.
// ---------------------------------------------------------------------------
__device__ inline float wave_red(float v) {
    #pragma unroll
    for (int off = 32; off > 0; off >>= 1) v += __shfl_down(v, off, 64);
    return v;
}

__global__ void __launch_bounds__(TPB) resolve_finalize(
        const float* __restrict__ pred,
        const float4* __restrict__ gt4,
        const float* __restrict__ thr,
        const unsigned int* __restrict__ good,
        const float* __restrict__ ow,
        const float* __restrict__ logits,
        float* __restrict__ accum,
        float* __restrict__ out,
        int M, int N) {
    __shared__ unsigned char verd[ROWS_PB];
    __shared__ int cands[ROWS_PB];
    __shared__ int ncand;
    int tid = threadIdx.x;
    int r0 = blockIdx.x * ROWS_PB;

    if (tid == 0) ncand = 0;
    __syncthreads();
    if (tid < ROWS_PB) {
        int i = r0 + tid;
        unsigned int gi = (i < M) ? good[i] : 0u;
        verd[tid] = (unsigned char)gi;
        if (gi) { int p = atomicAdd(&ncand, 1); cands[p] = tid; }
    }
    __syncthreads();
    int nc = ncand;

    for (int e = 0; e < nc; e++) {
        int r = r0 + cands[e];
        float p0 = pred[3*r+0], p1 = pred[3*r+1], p2 = pred[3*r+2];
        float sp;
        {
            #pragma clang fp contract(off)
            sp = (p0*p0 + p1*p1) + p2*p2;
        }
        float tp0 = 2.0f*p0, tp1 = 2.0f*p1, tp2 = 2.0f*p2;
        float dii = thr[r];
        bool h = false;
        #pragma unroll
        for (int half = 0; half < 2; half++) {
            int base = (half == 0) ? PRE_PB : (N + PRE_PB);
            int end  = (half == 0) ? N : M;
            for (int j0 = base + tid; j0 < end; j0 += TPB * RBATCH) {
                float4 g[RBATCH];
                #pragma unroll
                for (int b = 0; b < RBATCH; b++) {
                    int j = j0 + b * TPB;
                    g[b] = gt4[(j < end) ? j : base];   // pre-issued batch
                }
                #pragma unroll
                for (int b = 0; b < RBATCH; b++) {
                    int j = j0 + b * TPB;
                    float v = (sp + g[b].w) -
                              fmaf(tp2, g[b].z, fmaf(tp1, g[b].y, tp0 * g[b].x));
                    float c = fmaxf(v, 0.0f);
                    h = h || ((j < end) &&
                              ((c < dii && j != r) || (c == dii && j < r)));
                }
            }
        }
        if (h) verd[cands[e]] = 0;   // benign LDS race: only 0 is written
    }
    __syncthreads();

    // finalize this block's 64 rows (threads 0..63 == wave 0)
    float werr = 0.f, wsum = 0.f, b1 = 0.f, c1 = 0.f, b0 = 0.f, c0 = 0.f;
    if (tid < ROWS_PB && (r0 + tid) < M) {
        int i = r0 + tid;
        float x = logits[i];
        float l1p = log1pf(expf(-fabsf(x)));   // softplus tail
        if (verd[tid]) {                       // label 1: bce = softplus(-x)
            b1 = fmaxf(-x, 0.f) + l1p; c1 = 1.f;
        } else {                               // label 0: bce = softplus(x)
            b0 = fmaxf(x, 0.f) + l1p;  c0 = 1.f;
        }
        float4 g = gt4[i];
        float q0 = pred[3*i+0], q1 = pred[3*i+1], q2 = pred[3*i+2];
        float e2 = (fabsf(q0 - g.x) + fabsf(q1 - g.y)) + fabsf(q2 - g.z);
        float wi = ow[i];
        werr = wi * e2;
        wsum = wi;
    }
    werr = wave_red(werr); wsum = wave_red(wsum);
    b1 = wave_red(b1); c1 = wave_red(c1);
    b0 = wave_red(b0); c0 = wave_red(c0);
    if (tid == 0) {
        atomicAdd(&accum[0], werr);
        atomicAdd(&accum[1], wsum);
        atomicAdd(&accum[2], b1);
        atomicAdd(&accum[3], c1);
        atomicAdd(&accum[4], b0);
        atomicAdd(&accum[5], c0);
    }
    __threadfence();          // make this block's atomics device-visible
    __syncthreads();
    if (tid == 0) {
        unsigned int* ctr = (unsigned int*)&accum[7];
        unsigned int old = atomicAdd(ctr, 1u);
        if (old == gridDim.x - 1) {
            // atomic reads: guaranteed-coherent path for others' atomics
            float a0 = atomicAdd(&accum[0], 0.f);
            float a1 = atomicAdd(&accum[1], 0.f);
            float a2 = atomicAdd(&accum[2], 0.f);
            float a3 = atomicAdd(&accum[3], 0.f);
            float a4 = atomicAdd(&accum[4], 0.f);
            float a5 = atomicAdd(&accum[5], 0.f);
            float mean_err = a0 / fmaxf(a1, 1e-6f);
            float g1v = (a3 > 0.f) ? (a2 / fmaxf(a3, 1.f)) : 0.f;
            float g0v = (a5 > 0.f) ? (a4 / fmaxf(a5, 1.f)) : 0.f;
            out[0] = mean_err + (g0v * 0.5f + g1v * 0.5f);
        }
    }
}

extern "C" void kernel_launch(void* const* d_in, const int* in_sizes, int n_in,
                              void* d_out, int out_size, void* d_ws, size_t ws_size,
                              hipStream_t stream) {
    const float* kp_before = (const float*)d_in[0];
    const float* pred      = (const float*)d_in[1];
    const float* pose      = (const float*)d_in[2];
    const float* ow        = (const float*)d_in[3];
    const float* logits    = (const float*)d_in[4];
    float* out = (float*)d_out;

    int M = in_sizes[3];            // B*N = 16384
    int B = in_sizes[2] / 12;       // 2
    int N = M / B;                  // 8192

    char* ws = (char*)d_ws;
    float4* gt4 = (float4*)ws;                                  // M*16 B
    float* thr = (float*)(ws + (size_t)M * 16);                 // M*4 B
    unsigned int* good = (unsigned int*)(ws + (size_t)M * 20);  // M*4 B
    float* accum = (float*)(ws + (size_t)M * 24);               // 32 B ([7]=ticket)

    int nblk = (M + ROWS_PB - 1) / ROWS_PB;                     // 256 blocks

    hipLaunchKernelGGL(prep_prefix, dim3(nblk), dim3(TPB), 0, stream,
                       kp_before, pred, pose, gt4, thr, good, accum, M, N);

    hipLaunchKernelGGL(resolve_finalize, dim3(nblk), dim3(TPB), 0, stream,
                       pred, gt4, thr, good, ow, logits, accum, out, M, N);
}